// Round 5
// baseline (600.164 us; speedup 1.0000x reference)
//
#include <hip/hip_runtime.h>
#include <math.h>

#define B_   8
#define T_   256
#define U_   64
#define UP1  65
#define DE   640
#define J_   512
#define V_   1024
#define LOG0 -1e30f

typedef __attribute__((ext_vector_type(8))) short short8;
typedef __attribute__((ext_vector_type(4))) float f32x4;

__device__ __forceinline__ float lae(float a, float b) {
    float m = fmaxf(a, b);
    float d = fminf(a, b) - m;          // <= 0
    return m + __logf(1.f + __expf(d));
}

__device__ __forceinline__ unsigned short f2bf(float x) {
    union { float f; unsigned int u; } c; c.f = x;
    unsigned int r = (c.u + 0x7fffu + ((c.u >> 16) & 1u)) >> 16;  // RNE
    return (unsigned short)r;
}

// LDS swizzle for hB: row m (0..63), column byte offset cb (0..1023, 16B granular).
// XOR bits 4-6 with (m ^ cb>>7): staging writes (8 kslots/row) AND frag reads both 2-way.
__device__ __forceinline__ unsigned hb_off(unsigned m, unsigned cb) {
    return m * 1024u + (cb ^ ((((m ^ (cb >> 7)) & 7u) << 4)));
}

// ---------------- Kernel A: C[M x 512] = A[M x 640] * W[640 x 512] (+bias) -------------
__global__ __launch_bounds__(256) void gemm_in(const float* __restrict__ A,
                                               const float* __restrict__ W,
                                               const float* __restrict__ bias,
                                               float* __restrict__ C, int M) {
    __shared__ float As[16][64];
    __shared__ float Bs[16][64];
    int tid  = threadIdx.x;
    int row0 = blockIdx.x * 64;
    int col0 = blockIdx.y * 64;
    int tx = tid & 15, ty = tid >> 4;
    float acc[4][4] = {};
    int ar  = tid >> 2;
    int akq = tid & 3;
    int bkr = tid >> 4;
    int bcq = tid & 15;
    for (int k0 = 0; k0 < DE; k0 += 16) {
        float4 av = make_float4(0.f, 0.f, 0.f, 0.f);
        int arow = row0 + ar;
        if (arow < M) av = *(const float4*)&A[arow * DE + k0 + akq * 4];
        As[akq * 4 + 0][ar] = av.x;
        As[akq * 4 + 1][ar] = av.y;
        As[akq * 4 + 2][ar] = av.z;
        As[akq * 4 + 3][ar] = av.w;
        *(float4*)&Bs[bkr][bcq * 4] = *(const float4*)&W[(k0 + bkr) * J_ + col0 + bcq * 4];
        __syncthreads();
#pragma unroll
        for (int k = 0; k < 16; ++k) {
            float4 a4 = *(const float4*)&As[k][ty * 4];
            float4 b4 = *(const float4*)&Bs[k][tx * 4];
            float a[4] = {a4.x, a4.y, a4.z, a4.w};
            float b[4] = {b4.x, b4.y, b4.z, b4.w};
#pragma unroll
            for (int i = 0; i < 4; ++i)
#pragma unroll
                for (int j = 0; j < 4; ++j) acc[i][j] += a[i] * b[j];
        }
        __syncthreads();
    }
#pragma unroll
    for (int i = 0; i < 4; ++i) {
        int row = row0 + ty * 4 + i;
        if (row >= M) continue;
#pragma unroll
        for (int j = 0; j < 4; ++j) {
            int col = col0 + tx * 4 + j;
            float v = acc[i][j];
            if (bias) v += bias[col];
            C[row * J_ + col] = v;
        }
    }
}

// ---- Kernel W: W_out[512][1024] -> fragment-major bf16 Wf ----
// Wf layout (shorts): tile(=col>>4)*8192 + kt(=k>>5)*512 + (lg*16+ln)*8 + j
__global__ __launch_bounds__(256) void wt_kernel(const float* __restrict__ W,
                                                 unsigned short* __restrict__ Wf) {
    __shared__ float tile[32][33];
    int tx = threadIdx.x & 31, ty = threadIdx.x >> 5;  // 32x8
    int v0 = blockIdx.x * 32, k0 = blockIdx.y * 32;
#pragma unroll
    for (int i = 0; i < 4; ++i)
        tile[ty + i * 8][tx] = W[(size_t)(k0 + ty + i * 8) * V_ + v0 + tx];
    __syncthreads();
#pragma unroll
    for (int i = 0; i < 4; ++i) {
        int v = v0 + ty + i * 8;
        int k = k0 + tx;
        int tl = v >> 4, ln = v & 15;
        int kt = k >> 5, lg = (k & 31) >> 3, j = k & 7;
        Wf[tl * 8192 + kt * 512 + (lg * 16 + ln) * 8 + j] = f2bf(tile[tx][ty + i * 8]);
    }
}

// -------- Kernel B: MFMA joint. 64 cells x 1024 cols x K=512 per block (8 waves) -------
// wave wc owns cols [wc*128,+128): frag grid 4mi x 8ni of 16x16x32 bf16 MFMA.
// bf[2][8] per-ni interleaved prefetch; af[2][4] double-buffered LDS reads.
__global__ __launch_bounds__(512, 2) void joint_mfma(const float* __restrict__ ep,
                                                     const float* __restrict__ pp,
                                                     const unsigned short* __restrict__ Wf,
                                                     const float* __restrict__ bout,
                                                     const int* __restrict__ labels,
                                                     const int* __restrict__ pblank,
                                                     float* __restrict__ blp,
                                                     float* __restrict__ llp) {
    __shared__ __align__(16) unsigned char hB[64 * 1024];  // h[64][512] bf16, swizzled
    __shared__ float ps[8][64];
    __shared__ float lseA[64];

    int tid = threadIdx.x;
    int c0  = blockIdx.x * 64;

    // ---- stage h = tanh(ep+pp) as bf16 ----
    {
        int row   = tid >> 3;
        int kslot = tid & 7;
        int cell  = c0 + row;
        unsigned epRow = (unsigned)cell / 65u;
        int u = cell - (int)epRow * 65;
        int b = (int)(epRow >> 8);
        const float* epr = ep + (size_t)epRow * J_ + kslot * 64;
        const float* ppr = pp + (size_t)(b * UP1 + u) * J_ + kslot * 64;
#pragma unroll
        for (int c8 = 0; c8 < 8; ++c8) {
            float4 e0 = *(const float4*)(epr + c8 * 8);
            float4 e1 = *(const float4*)(epr + c8 * 8 + 4);
            float4 p0 = *(const float4*)(ppr + c8 * 8);
            float4 p1 = *(const float4*)(ppr + c8 * 8 + 4);
            float x[8] = {e0.x + p0.x, e0.y + p0.y, e0.z + p0.z, e0.w + p0.w,
                          e1.x + p1.x, e1.y + p1.y, e1.z + p1.z, e1.w + p1.w};
            short8 hv;
#pragma unroll
            for (int j = 0; j < 8; ++j) {
                float e2 = __expf(2.f * x[j]);
                float t  = 1.f - 2.f / (e2 + 1.f);
                hv[j] = (short)f2bf(t);
            }
            unsigned cb = (unsigned)(kslot * 128 + c8 * 16);
            *(short8*)(hB + hb_off((unsigned)row, cb)) = hv;
        }
    }
    __syncthreads();

    int wc = tid >> 6, lane = tid & 63;
    int lg = lane >> 4, ln = lane & 15;

    f32x4 acc[4][8] = {};

    // per-wave fragment-major base: short8 index = (wc*8+ni)*1024 + kt*64 + lane
    const short8* wfb = (const short8*)Wf + (wc << 13) + lane;

    short8 bf[2][8];
    short8 af[2][4];
#pragma unroll
    for (int ni = 0; ni < 8; ++ni) bf[0][ni] = wfb[ni * 1024];
#pragma unroll
    for (int mi = 0; mi < 4; ++mi) {
        unsigned m  = (unsigned)(mi * 16 + ln);
        unsigned cb = (unsigned)(lg * 16);
        af[0][mi] = *(const short8*)(hB + hb_off(m, cb));
    }

#pragma unroll
    for (int kt = 0; kt < 16; ++kt) {
        const int cur = kt & 1, nxt = cur ^ 1;
#pragma unroll
        for (int ni = 0; ni < 8; ++ni) {
            if (kt < 15) bf[nxt][ni] = wfb[ni * 1024 + (kt + 1) * 64];
            __builtin_amdgcn_s_setprio(1);
#pragma unroll
            for (int mi = 0; mi < 4; ++mi)
                acc[mi][ni] = __builtin_amdgcn_mfma_f32_16x16x32_bf16(
                    af[cur][mi], bf[cur][ni], acc[mi][ni], 0, 0, 0);
            __builtin_amdgcn_s_setprio(0);
            if (ni == 3 && kt < 15) {
#pragma unroll
                for (int mi = 0; mi < 4; ++mi) {
                    unsigned m  = (unsigned)(mi * 16 + ln);
                    unsigned cb = (unsigned)((kt + 1) * 64 + lg * 16);
                    af[nxt][mi] = *(const short8*)(hB + hb_off(m, cb));
                }
            }
        }
    }

    // ---- epilogue: bias, exp-sum (|logits| small: no max needed), lse, gather ----
    float bo[8];
#pragma unroll
    for (int ni = 0; ni < 8; ++ni) bo[ni] = bout[(wc << 7) + (ni << 4) + ln];
#pragma unroll
    for (int mi = 0; mi < 4; ++mi)
#pragma unroll
        for (int ni = 0; ni < 8; ++ni)
#pragma unroll
            for (int r = 0; r < 4; ++r) acc[mi][ni][r] += bo[ni];

#pragma unroll
    for (int mi = 0; mi < 4; ++mi) {
#pragma unroll
        for (int r = 0; r < 4; ++r) {
            float s = 0.f;
#pragma unroll
            for (int ni = 0; ni < 8; ++ni) s += __expf(acc[mi][ni][r]);
            s += __shfl_xor(s, 1);
            s += __shfl_xor(s, 2);
            s += __shfl_xor(s, 4);
            s += __shfl_xor(s, 8);
            if (ln == 0) ps[wc][mi * 16 + lg * 4 + r] = s;
        }
    }
    __syncthreads();
    if (tid < 64) {
        float S = 0.f;
#pragma unroll
        for (int w2 = 0; w2 < 8; ++w2) S += ps[w2][tid];
        lseA[tid] = __logf(S);
    }
    __syncthreads();

    int blank = *pblank;
#pragma unroll
    for (int mi = 0; mi < 4; ++mi) {
#pragma unroll
        for (int r = 0; r < 4; ++r) {
            int row  = mi * 16 + lg * 4 + r;
            int cell = c0 + row;
            unsigned epRow = (unsigned)cell / 65u;
            int u = cell - (int)epRow * 65;
            int b = (int)(epRow >> 8);
            int lab = (u < U_) ? labels[(b << 6) + u] : -1;
            float lse = lseA[row];
#pragma unroll
            for (int ni = 0; ni < 8; ++ni) {
                int col  = (wc << 7) + (ni << 4) + ln;
                float lp = acc[mi][ni][r] - lse;
                if (col == blank) blp[cell] = lp;
                if (col == lab)   llp[(size_t)(((int)epRow << 6) + u)] = lp;
            }
        }
    }
}

// ---------------- Kernel C: alpha scan over T, one wave per batch element --------------
__global__ __launch_bounds__(512) void scan_kernel(const float* __restrict__ blp,
                                                   const float* __restrict__ llp,
                                                   const int* __restrict__ enc_lens,
                                                   const int* __restrict__ label_lens,
                                                   float* __restrict__ out) {
    __shared__ float lossArr[B_];
    int tid  = threadIdx.x;
    int b    = tid >> 6;
    int lane = tid & 63;
    int el = enc_lens[b];
    int ll = label_lens[b];
    float alpha   = (lane == 0) ? 0.f : LOG0;
    float alpha64 = LOG0;
    const float* bb = &blp[(size_t)b * T_ * UP1];
    const float* lb = &llp[(size_t)b * T_ * U_];

    for (int t = 0; t < T_; ++t) {
        if (t < el) {
            float bv   = bb[t * UP1 + lane];
            float bv64 = (lane == 63) ? bb[t * UP1 + 64] : 0.f;
            float lv   = lb[t * U_ + lane];
            float P = lv;
#pragma unroll
            for (int d = 1; d < 64; d <<= 1) {
                float v = __shfl(P, lane - d);
                if (lane >= d) P += v;
            }
            float L = __shfl(P, lane - 1);
            if (lane == 0) L = 0.f;
            float c = alpha + bv;
            float x = c - L;
            float s = x;
#pragma unroll
            for (int d = 1; d < 64; d <<= 1) {
                float v = __shfl(s, lane - d);
                if (lane >= d) s = lae(s, v);
            }
            float c64 = alpha64 + bv64;
            float x64 = c64 - P;
            float s64 = lae(s, x64);
            float a64 = P + s64;
            alpha = L + s;
            if (lane == 63) alpha64 = a64;
        }
    }

    float term  = bb[(el - 1) * UP1 + ll];
    float a_ll  = __shfl(alpha, (ll < 64) ? ll : 63);
    float a_64v = __shfl(alpha64, 63);
    float aU    = (ll < 64) ? a_ll : a_64v;
    if (lane == 0) lossArr[b] = -(aU + term);
    __syncthreads();
    if (tid == 0) {
        float s = 0.f;
        for (int i = 0; i < B_; ++i) s += lossArr[i];
        out[0] = s / (float)B_;
    }
}

extern "C" void kernel_launch(void* const* d_in, const int* in_sizes, int n_in,
                              void* d_out, int out_size, void* d_ws, size_t ws_size,
                              hipStream_t stream) {
    (void)in_sizes; (void)n_in; (void)out_size; (void)ws_size;
    const float* enc        = (const float*)d_in[0];
    const float* pred       = (const float*)d_in[1];
    const float* W_enc      = (const float*)d_in[2];
    const float* W_pred     = (const float*)d_in[3];
    const float* b_joint    = (const float*)d_in[4];
    const float* W_out      = (const float*)d_in[5];
    const float* b_out      = (const float*)d_in[6];
    const int*   labels     = (const int*)d_in[7];
    const int*   enc_lens   = (const int*)d_in[8];
    const int*   label_lens = (const int*)d_in[9];
    const int*   blank_id   = (const int*)d_in[10];

    float* ep  = (float*)d_ws;                      // B*T*J   = 1,048,576 f
    float* pp  = ep  + (size_t)B_ * T_ * J_;        // B*65*J  =   266,240 f
    float* blp = pp  + (size_t)B_ * UP1 * J_;       // B*T*65  =   133,120 f
    float* llp = blp + (size_t)B_ * T_ * UP1;       // B*T*64  =   131,072 f
    unsigned short* Wf = (unsigned short*)(llp + (size_t)B_ * T_ * U_);  // 1MB frag-major

    wt_kernel<<<dim3(V_ / 32, J_ / 32), dim3(256), 0, stream>>>(W_out, Wf);
    gemm_in<<<dim3((B_ * T_ + 63) / 64, J_ / 64), dim3(256), 0, stream>>>(
        enc, W_enc, b_joint, ep, B_ * T_);
    gemm_in<<<dim3((B_ * UP1 + 63) / 64, J_ / 64), dim3(256), 0, stream>>>(
        pred, W_pred, nullptr, pp, B_ * UP1);
    joint_mfma<<<dim3(B_ * T_ * UP1 / 64), dim3(512), 0, stream>>>(
        ep, pp, Wf, b_out, labels, blank_id, blp, llp);
    scan_kernel<<<dim3(1), dim3(512), 0, stream>>>(blp, llp, enc_lens, label_lens,
                                                   (float*)d_out);
}

// Round 6
// 590.925 us; speedup vs baseline: 1.0156x; 1.0156x over previous
//
#include <hip/hip_runtime.h>
#include <math.h>

#define B_   8
#define T_   256
#define U_   64
#define UP1  65
#define DE   640
#define J_   512
#define V_   1024
#define LOG0 -1e30f

typedef __attribute__((ext_vector_type(4))) float f32x4;

__device__ __forceinline__ float lae(float a, float b) {
    float m = fmaxf(a, b);
    float d = fminf(a, b) - m;          // <= 0
    return m + __logf(1.f + __expf(d));
}

// LDS swizzle for fp8 hB: row m (0..63, 512B rows), cb = column byte offset (8B granular).
// XOR bits 3-6 with m&15: optimal (4 lanes / 8B slot) for BOTH staging writes and frag reads.
__device__ __forceinline__ unsigned hb8(unsigned m, unsigned cb) {
    return m * 512u + (cb ^ ((m & 15u) << 3));
}

// ---------------- Kernel A: C[M x 512] = A[M x 640] * W[640 x 512] (+bias) -------------
__global__ __launch_bounds__(256) void gemm_in(const float* __restrict__ A,
                                               const float* __restrict__ W,
                                               const float* __restrict__ bias,
                                               float* __restrict__ C, int M) {
    __shared__ float As[16][64];
    __shared__ float Bs[16][64];
    int tid  = threadIdx.x;
    int row0 = blockIdx.x * 64;
    int col0 = blockIdx.y * 64;
    int tx = tid & 15, ty = tid >> 4;
    float acc[4][4] = {};
    int ar  = tid >> 2;
    int akq = tid & 3;
    int bkr = tid >> 4;
    int bcq = tid & 15;
    for (int k0 = 0; k0 < DE; k0 += 16) {
        float4 av = make_float4(0.f, 0.f, 0.f, 0.f);
        int arow = row0 + ar;
        if (arow < M) av = *(const float4*)&A[arow * DE + k0 + akq * 4];
        As[akq * 4 + 0][ar] = av.x;
        As[akq * 4 + 1][ar] = av.y;
        As[akq * 4 + 2][ar] = av.z;
        As[akq * 4 + 3][ar] = av.w;
        *(float4*)&Bs[bkr][bcq * 4] = *(const float4*)&W[(k0 + bkr) * J_ + col0 + bcq * 4];
        __syncthreads();
#pragma unroll
        for (int k = 0; k < 16; ++k) {
            float4 a4 = *(const float4*)&As[k][ty * 4];
            float4 b4 = *(const float4*)&Bs[k][tx * 4];
            float a[4] = {a4.x, a4.y, a4.z, a4.w};
            float b[4] = {b4.x, b4.y, b4.z, b4.w};
#pragma unroll
            for (int i = 0; i < 4; ++i)
#pragma unroll
                for (int j = 0; j < 4; ++j) acc[i][j] += a[i] * b[j];
        }
        __syncthreads();
    }
#pragma unroll
    for (int i = 0; i < 4; ++i) {
        int row = row0 + ty * 4 + i;
        if (row >= M) continue;
#pragma unroll
        for (int j = 0; j < 4; ++j) {
            int col = col0 + tx * 4 + j;
            float v = acc[i][j];
            if (bias) v += bias[col];
            C[row * J_ + col] = v;
        }
    }
}

// ---- Kernel W: W_out[512][1024] -> fragment-major fp8(e4m3) Wf ----
// Wf byte layout: tl(=col>>4)*8192 + kt(=k>>5)*512 + (lg*16+ln)*8 + j
// where ln=col&15, lg=(k&31)>>3, j=k&7. Wave bfrag load = 512B contiguous.
__global__ __launch_bounds__(256) void wt_kernel(const float* __restrict__ W,
                                                 unsigned char* __restrict__ Wf) {
    __shared__ float tile[32][33];
    int tid = threadIdx.x;
    int tx = tid & 31, ty = tid >> 5;  // 32x8
    int v0 = blockIdx.x * 32, k0 = blockIdx.y * 32;
#pragma unroll
    for (int i = 0; i < 4; ++i)
        tile[ty + i * 8][tx] = W[(size_t)(k0 + ty + i * 8) * V_ + v0 + tx];  // [k_loc][v_loc]
    __syncthreads();
    if (tid < 128) {
        int vl = tid >> 2, lg = tid & 3;
        int v  = v0 + vl;
        float x[8];
#pragma unroll
        for (int j = 0; j < 8; ++j) x[j] = tile[lg * 8 + j][vl];
        int lo = 0, hi = 0;
        lo = __builtin_amdgcn_cvt_pk_fp8_f32(x[0], x[1], lo, false);
        lo = __builtin_amdgcn_cvt_pk_fp8_f32(x[2], x[3], lo, true);
        hi = __builtin_amdgcn_cvt_pk_fp8_f32(x[4], x[5], hi, false);
        hi = __builtin_amdgcn_cvt_pk_fp8_f32(x[6], x[7], hi, true);
        int tl = v >> 4, ln = v & 15, kt = k0 >> 5;
        *(int2*)(Wf + tl * 8192 + kt * 512 + (lg * 16 + ln) * 8) = make_int2(lo, hi);
    }
}

// -------- Kernel B: fp8 MFMA joint. 64 cells x 1024 cols x K=512 per block (8 waves) ---
// wave wc owns cols [wc*128,+128): frag grid 4mi x 8ni of 16x16x32 fp8 MFMA.
// bf[3][8] 2-kt-deep rotating prefetch; af[2][4] double-buffered LDS reads.
__global__ __launch_bounds__(512, 2) void joint_mfma(const float* __restrict__ ep,
                                                     const float* __restrict__ pp,
                                                     const unsigned char* __restrict__ Wf,
                                                     const float* __restrict__ bout,
                                                     const int* __restrict__ labels,
                                                     const int* __restrict__ pblank,
                                                     float* __restrict__ blp,
                                                     float* __restrict__ llp) {
    __shared__ __align__(16) unsigned char hB[64 * 512];  // h[64][512] fp8, swizzled
    __shared__ float ps[8][64];
    __shared__ float lseA[64];

    int tid = threadIdx.x;
    int c0  = blockIdx.x * 64;

    // ---- stage h = tanh(ep+pp) as fp8 ----
    {
        int row   = tid >> 3;
        int kslot = tid & 7;
        int cell  = c0 + row;
        unsigned epRow = (unsigned)cell / 65u;
        int u = cell - (int)epRow * 65;
        int b = (int)(epRow >> 8);
        const float* epr = ep + (size_t)epRow * J_ + kslot * 64;
        const float* ppr = pp + (size_t)(b * UP1 + u) * J_ + kslot * 64;
#pragma unroll
        for (int c8 = 0; c8 < 8; ++c8) {
            float4 e0 = *(const float4*)(epr + c8 * 8);
            float4 e1 = *(const float4*)(epr + c8 * 8 + 4);
            float4 p0 = *(const float4*)(ppr + c8 * 8);
            float4 p1 = *(const float4*)(ppr + c8 * 8 + 4);
            float x[8] = {e0.x + p0.x, e0.y + p0.y, e0.z + p0.z, e0.w + p0.w,
                          e1.x + p1.x, e1.y + p1.y, e1.z + p1.z, e1.w + p1.w};
            float t[8];
#pragma unroll
            for (int j = 0; j < 8; ++j) {
                float e2 = __expf(2.f * x[j]);
                t[j] = 1.f - 2.f / (e2 + 1.f);
            }
            int lo = 0, hi = 0;
            lo = __builtin_amdgcn_cvt_pk_fp8_f32(t[0], t[1], lo, false);
            lo = __builtin_amdgcn_cvt_pk_fp8_f32(t[2], t[3], lo, true);
            hi = __builtin_amdgcn_cvt_pk_fp8_f32(t[4], t[5], hi, false);
            hi = __builtin_amdgcn_cvt_pk_fp8_f32(t[6], t[7], hi, true);
            unsigned cb = (unsigned)(kslot * 64 + c8 * 8);
            *(int2*)(hB + hb8((unsigned)row, cb)) = make_int2(lo, hi);
        }
    }
    __syncthreads();

    int wc = tid >> 6, lane = tid & 63;
    int lg = lane >> 4, ln = lane & 15;

    f32x4 acc[4][8] = {};

    // frag-major Wf as longs: index = (wc*8+ni)*1024 + kt*64 + lane
    const long* wfbL = (const long*)Wf + (wc << 13) + lane;

    long bf[3][8];
    long af[2][4];
#pragma unroll
    for (int ni = 0; ni < 8; ++ni) bf[0][ni] = wfbL[ni * 1024];
#pragma unroll
    for (int ni = 0; ni < 8; ++ni) bf[1][ni] = wfbL[ni * 1024 + 64];
#pragma unroll
    for (int mi = 0; mi < 4; ++mi) {
        unsigned m  = (unsigned)(mi * 16 + ln);
        unsigned cb = (unsigned)(lg * 8);
        af[0][mi] = *(const long*)(hB + hb8(m, cb));
    }

#pragma unroll
    for (int kt = 0; kt < 16; ++kt) {
        const int cur3 = kt % 3;
        const int pf3  = (kt + 2) % 3;
        const int cur  = kt & 1, nxt = cur ^ 1;
#pragma unroll
        for (int ni = 0; ni < 8; ++ni) {
            if (kt < 14) bf[pf3][ni] = wfbL[ni * 1024 + (kt + 2) * 64];
            __builtin_amdgcn_s_setprio(1);
#pragma unroll
            for (int mi = 0; mi < 4; ++mi)
                acc[mi][ni] = __builtin_amdgcn_mfma_f32_16x16x32_fp8_fp8(
                    af[cur][mi], bf[cur3][ni], acc[mi][ni], 0, 0, 0);
            __builtin_amdgcn_s_setprio(0);
            if (ni == 3 && kt < 15) {
#pragma unroll
                for (int mi = 0; mi < 4; ++mi) {
                    unsigned m  = (unsigned)(mi * 16 + ln);
                    unsigned cb = (unsigned)((kt + 1) * 32 + lg * 8);
                    af[nxt][mi] = *(const long*)(hB + hb8(m, cb));
                }
            }
        }
    }

    // ---- epilogue: bias, exp-sum (|logits| small: no max needed), lse, gather ----
    float bo[8];
#pragma unroll
    for (int ni = 0; ni < 8; ++ni) bo[ni] = bout[(wc << 7) + (ni << 4) + ln];
#pragma unroll
    for (int mi = 0; mi < 4; ++mi)
#pragma unroll
        for (int ni = 0; ni < 8; ++ni)
#pragma unroll
            for (int r = 0; r < 4; ++r) acc[mi][ni][r] += bo[ni];

#pragma unroll
    for (int mi = 0; mi < 4; ++mi) {
#pragma unroll
        for (int r = 0; r < 4; ++r) {
            float s = 0.f;
#pragma unroll
            for (int ni = 0; ni < 8; ++ni) s += __expf(acc[mi][ni][r]);
            s += __shfl_xor(s, 1);
            s += __shfl_xor(s, 2);
            s += __shfl_xor(s, 4);
            s += __shfl_xor(s, 8);
            if (ln == 0) ps[wc][mi * 16 + lg * 4 + r] = s;
        }
    }
    __syncthreads();
    if (tid < 64) {
        float S = 0.f;
#pragma unroll
        for (int w2 = 0; w2 < 8; ++w2) S += ps[w2][tid];
        lseA[tid] = __logf(S);
    }
    __syncthreads();

    int blank = *pblank;
#pragma unroll
    for (int mi = 0; mi < 4; ++mi) {
#pragma unroll
        for (int r = 0; r < 4; ++r) {
            int row  = mi * 16 + lg * 4 + r;
            int cell = c0 + row;
            unsigned epRow = (unsigned)cell / 65u;
            int u = cell - (int)epRow * 65;
            int b = (int)(epRow >> 8);
            int lab = (u < U_) ? labels[(b << 6) + u] : -1;
            float lse = lseA[row];
#pragma unroll
            for (int ni = 0; ni < 8; ++ni) {
                int col  = (wc << 7) + (ni << 4) + ln;
                float lp = acc[mi][ni][r] - lse;
                if (col == blank) blp[cell] = lp;
                if (col == lab)   llp[(size_t)(((int)epRow << 6) + u)] = lp;
            }
        }
    }
}

// ---------------- Kernel C: alpha scan over T, one wave per batch element --------------
__global__ __launch_bounds__(512) void scan_kernel(const float* __restrict__ blp,
                                                   const float* __restrict__ llp,
                                                   const int* __restrict__ enc_lens,
                                                   const int* __restrict__ label_lens,
                                                   float* __restrict__ out) {
    __shared__ float lossArr[B_];
    int tid  = threadIdx.x;
    int b    = tid >> 6;
    int lane = tid & 63;
    int el = enc_lens[b];
    int ll = label_lens[b];
    float alpha   = (lane == 0) ? 0.f : LOG0;
    float alpha64 = LOG0;
    const float* bb = &blp[(size_t)b * T_ * UP1];
    const float* lb = &llp[(size_t)b * T_ * U_];

    for (int t = 0; t < T_; ++t) {
        if (t < el) {
            float bv   = bb[t * UP1 + lane];
            float bv64 = (lane == 63) ? bb[t * UP1 + 64] : 0.f;
            float lv   = lb[t * U_ + lane];
            float P = lv;
#pragma unroll
            for (int d = 1; d < 64; d <<= 1) {
                float v = __shfl(P, lane - d);
                if (lane >= d) P += v;
            }
            float L = __shfl(P, lane - 1);
            if (lane == 0) L = 0.f;
            float c = alpha + bv;
            float x = c - L;
            float s = x;
#pragma unroll
            for (int d = 1; d < 64; d <<= 1) {
                float v = __shfl(s, lane - d);
                if (lane >= d) s = lae(s, v);
            }
            float c64 = alpha64 + bv64;
            float x64 = c64 - P;
            float s64 = lae(s, x64);
            float a64 = P + s64;
            alpha = L + s;
            if (lane == 63) alpha64 = a64;
        }
    }

    float term  = bb[(el - 1) * UP1 + ll];
    float a_ll  = __shfl(alpha, (ll < 64) ? ll : 63);
    float a_64v = __shfl(alpha64, 63);
    float aU    = (ll < 64) ? a_ll : a_64v;
    if (lane == 0) lossArr[b] = -(aU + term);
    __syncthreads();
    if (tid == 0) {
        float s = 0.f;
        for (int i = 0; i < B_; ++i) s += lossArr[i];
        out[0] = s / (float)B_;
    }
}

extern "C" void kernel_launch(void* const* d_in, const int* in_sizes, int n_in,
                              void* d_out, int out_size, void* d_ws, size_t ws_size,
                              hipStream_t stream) {
    (void)in_sizes; (void)n_in; (void)out_size; (void)ws_size;
    const float* enc        = (const float*)d_in[0];
    const float* pred       = (const float*)d_in[1];
    const float* W_enc      = (const float*)d_in[2];
    const float* W_pred     = (const float*)d_in[3];
    const float* b_joint    = (const float*)d_in[4];
    const float* W_out      = (const float*)d_in[5];
    const float* b_out      = (const float*)d_in[6];
    const int*   labels     = (const int*)d_in[7];
    const int*   enc_lens   = (const int*)d_in[8];
    const int*   label_lens = (const int*)d_in[9];
    const int*   blank_id   = (const int*)d_in[10];

    float* ep  = (float*)d_ws;                      // B*T*J   = 1,048,576 f
    float* pp  = ep  + (size_t)B_ * T_ * J_;        // B*65*J  =   266,240 f
    float* blp = pp  + (size_t)B_ * UP1 * J_;       // B*T*65  =   133,120 f
    float* llp = blp + (size_t)B_ * T_ * UP1;       // B*T*64  =   131,072 f
    unsigned char* Wf = (unsigned char*)(llp + (size_t)B_ * T_ * U_);  // 512KB frag-major fp8

    wt_kernel<<<dim3(V_ / 32, J_ / 32), dim3(256), 0, stream>>>(W_out, Wf);
    gemm_in<<<dim3((B_ * T_ + 63) / 64, J_ / 64), dim3(256), 0, stream>>>(
        enc, W_enc, b_joint, ep, B_ * T_);
    gemm_in<<<dim3((B_ * UP1 + 63) / 64, J_ / 64), dim3(256), 0, stream>>>(
        pred, W_pred, nullptr, pp, B_ * UP1);
    joint_mfma<<<dim3(B_ * T_ * UP1 / 64), dim3(512), 0, stream>>>(
        ep, pp, Wf, b_out, labels, blank_id, blp, llp);
    scan_kernel<<<dim3(1), dim3(512), 0, stream>>>(blp, llp, enc_lens, label_lens,
                                                   (float*)d_out);
}